// Round 4
// baseline (136.762 us; speedup 1.0000x reference)
//
#include <hip/hip_runtime.h>

#define B_    4
#define N_    512
#define IND_  300
#define H_    128
#define QQ    8          // queries per attention block
#define KC    16         // k-chunks -> 4096 blocks = 32 waves/CU (full occupancy)
#define RR    4          // rows per prep block (amortizes weight reads 4x)
#define LOG2E 1.4426950408889634f

// ---------------------------------------------------------------------------
// Packing: transpose weights to [i/4][t][4] float4 tiles (coalesced dwordx4
// in prep). Wa/Ua pre-scaled by log2e so prep uses raw exp2.
// ---------------------------------------------------------------------------
__global__ void pack_all(const float* __restrict__ Wx_w,
                         const float* __restrict__ Wa_w,
                         const float* __restrict__ Ua_w,
                         float* __restrict__ WxT4,
                         float* __restrict__ WaT4,
                         float* __restrict__ UaT4) {
    const int blk = blockIdx.x;
    const int t   = threadIdx.x;
    if (blk < IND_) {
        const int i = blk;
        WxT4[(i >> 2) * 512 + t * 4 + (i & 3)] = Wx_w[t * IND_ + i];
    } else if (blk < IND_ + H_) {
        const int i = blk - IND_;
        WaT4[(i >> 2) * 512 + t * 4 + (i & 3)] = Wa_w[t * H_ + i] * LOG2E;
    } else {
        const int i = blk - IND_ - H_;
        UaT4[(i >> 2) * 512 + t * 4 + (i & 3)] = Ua_w[t * H_ + i] * LOG2E;
    }
}

// ---------------------------------------------------------------------------
// Prep, RR rows per block: h = tanh(x.Wx^T + bx)
//   Eta = exp(h.Wa^T + ba)                         [B*N, H]
//   kv  = {Et=exp(h.Ua^T+bu), M=exp(mask), M*h, 0} [B*N, H]
// Weight loads coalesced dwordx4, reused across RR rows; x and h staged in
// LDS (same-address broadcast reads, conflict-free).
// ---------------------------------------------------------------------------
__global__ __launch_bounds__(128) void prep4(
    const float* __restrict__ x,      // [B*N, IND]
    const float* __restrict__ WxT4,   // [75][128][4]
    const float* __restrict__ Wx_b,
    const float* __restrict__ WaT4,   // [32][128][4], pre-scaled log2e
    const float* __restrict__ Wa_b,
    const float* __restrict__ UaT4,   // [32][128][4], pre-scaled log2e
    const float* __restrict__ Ua_b,
    const float* __restrict__ mask,   // [B*N, H]
    float* __restrict__ Eta,          // [B*N, H]
    float4* __restrict__ kv)          // [B*N, H]
{
    __shared__ __align__(16) float xs[RR * IND_];   // 4*300 floats, rows 16B-aligned
    __shared__ __align__(16) float hs[RR][H_];

    const int r0 = blockIdx.x * RR;
    const int t  = threadIdx.x;

    // RR consecutive x rows are contiguous: copy as float4 (300*4B % 16 == 0)
    const float4* xg = (const float4*)(x + (size_t)r0 * IND_);
    float4* xs4 = (float4*)xs;
    #pragma unroll
    for (int i = t; i < RR * IND_ / 4; i += 128) xs4[i] = xg[i];
    __syncthreads();

    // Phase A: h[r][t] = tanh(sum_i x[r][i] * Wx[t][i] + bx[t])
    float acc[RR];
    {
        const float bx = Wx_b[t];
        #pragma unroll
        for (int r = 0; r < RR; ++r) acc[r] = bx;
    }
    const float4* w4 = (const float4*)WxT4 + t;
    #pragma unroll 5
    for (int i4 = 0; i4 < IND_ / 4; ++i4) {
        float4 w = w4[i4 * 128];
        #pragma unroll
        for (int r = 0; r < RR; ++r) {
            float4 xv = *(const float4*)(xs + r * IND_ + 4 * i4);
            acc[r] = fmaf(w.x, xv.x, acc[r]);
            acc[r] = fmaf(w.y, xv.y, acc[r]);
            acc[r] = fmaf(w.z, xv.z, acc[r]);
            acc[r] = fmaf(w.w, xv.w, acc[r]);
        }
    }
    #pragma unroll
    for (int r = 0; r < RR; ++r) hs[r][t] = tanhf(acc[r]);
    __syncthreads();

    // Phase B: ta' = (h.Wa^T + ba)*log2e ; tb' likewise with Ua.
    float accA[RR], accU[RR];
    {
        const float ba = Wa_b[t] * LOG2E;
        const float bu = Ua_b[t] * LOG2E;
        #pragma unroll
        for (int r = 0; r < RR; ++r) { accA[r] = ba; accU[r] = bu; }
    }
    const float4* wa4 = (const float4*)WaT4 + t;
    const float4* ua4 = (const float4*)UaT4 + t;
    #pragma unroll 4
    for (int i4 = 0; i4 < H_ / 4; ++i4) {
        float4 wa = wa4[i4 * 128];
        float4 ua = ua4[i4 * 128];
        #pragma unroll
        for (int r = 0; r < RR; ++r) {
            float4 hv = *(const float4*)(&hs[r][4 * i4]);
            accA[r] = fmaf(wa.x, hv.x, accA[r]);
            accA[r] = fmaf(wa.y, hv.y, accA[r]);
            accA[r] = fmaf(wa.z, hv.z, accA[r]);
            accA[r] = fmaf(wa.w, hv.w, accA[r]);
            accU[r] = fmaf(ua.x, hv.x, accU[r]);
            accU[r] = fmaf(ua.y, hv.y, accU[r]);
            accU[r] = fmaf(ua.z, hv.z, accU[r]);
            accU[r] = fmaf(ua.w, hv.w, accU[r]);
        }
    }
    #pragma unroll
    for (int r = 0; r < RR; ++r) {
        const size_t o = (size_t)(r0 + r) * H_ + t;
        Eta[o]  = __builtin_amdgcn_exp2f(accA[r]);
        float M = __builtin_amdgcn_exp2f(mask[o] * LOG2E);
        float h = hs[r][t];
        kv[o]   = make_float4(__builtin_amdgcn_exp2f(accU[r]), M, M * h, 0.f);
    }
}

// ---------------------------------------------------------------------------
// Attention, one exp + 6 VALU per score:
//   e  = Eta[q,h] * Et[k,h]           (= exp(ta+tb))
//   p0 = (e > 1) ? e : exp(e - 1)     (= exp(elu(ta+tb)))
//   l  = fma(p0, M,  l)               (mask folded: p = p0*M)
//   c  = fma(p0, Mh, c)               (Mh = M*hv precomputed)
// ---------------------------------------------------------------------------
__global__ __launch_bounds__(128) void attn4(
    const float* __restrict__ Eta,    // [B*N, H]
    const float4* __restrict__ kv,    // [B*N, H] {Et, M, Mh, 0}
    float2* __restrict__ accum)       // [KC, B*N, H] {l, c}
{
    const int c  = blockIdx.x;        // 0..KC-1
    const int qg = blockIdx.y;        // 0..N/QQ-1
    const int b  = blockIdx.z;        // 0..B-1
    const int h  = threadIdx.x;
    const int q0 = qg * QQ;
    const int k0 = c * (N_ / KC);

    float eta[QQ], l[QQ], cc[QQ];
    #pragma unroll
    for (int j = 0; j < QQ; ++j) {
        eta[j] = Eta[((size_t)(b * N_ + q0 + j)) * H_ + h];
        l[j] = 0.f;
        cc[j] = 0.f;
    }

    const float4* kp = kv + ((size_t)(b * N_ + k0)) * H_ + h;

    #pragma unroll 4
    for (int k = 0; k < N_ / KC; ++k) {
        float4 v = kp[(size_t)k * H_];          // {Et, M, Mh, 0}
        #pragma unroll
        for (int j = 0; j < QQ; ++j) {
            float e  = eta[j] * v.x;
            float pn = __builtin_amdgcn_exp2f(fmaf(e, LOG2E, -LOG2E));
            float p0 = (e > 1.f) ? e : pn;
            l[j]  = fmaf(p0, v.y, l[j]);
            cc[j] = fmaf(p0, v.z, cc[j]);
        }
    }

    #pragma unroll
    for (int j = 0; j < QQ; ++j) {
        accum[((size_t)c * (B_ * N_) + b * N_ + q0 + j) * H_ + h] =
            make_float2(l[j], cc[j]);
    }
}

__global__ void fin4(const float2* __restrict__ accum, float* __restrict__ out) {
    const int idx = blockIdx.x * 256 + threadIdx.x;   // B*N*H threads
    float L = 0.f, C = 0.f;
    #pragma unroll
    for (int c = 0; c < KC; ++c) {
        float2 a = accum[(size_t)c * (B_ * N_ * H_) + idx];
        L += a.x;
        C += a.y;
    }
    out[idx] = C / L;
}

extern "C" void kernel_launch(void* const* d_in, const int* in_sizes, int n_in,
                              void* d_out, int out_size, void* d_ws, size_t ws_size,
                              hipStream_t stream) {
    const float* word_vecs = (const float*)d_in[0];
    const float* mask      = (const float*)d_in[1];
    const float* Wx_w      = (const float*)d_in[2];
    const float* Wx_b      = (const float*)d_in[3];
    const float* Wa_w      = (const float*)d_in[4];
    const float* Wa_b      = (const float*)d_in[5];
    const float* Ua_w      = (const float*)d_in[6];
    const float* Ua_b      = (const float*)d_in[7];
    float* out = (float*)d_out;

    // workspace layout (16B aligned): ~37.3 MB total
    char* p = (char*)d_ws;
    float*  WxT4  = (float*)p;   p += (size_t)75 * 512 * 4;               // 153.6 KB
    float*  WaT4  = (float*)p;   p += (size_t)32 * 512 * 4;               // 64 KB
    float*  UaT4  = (float*)p;   p += (size_t)32 * 512 * 4;               // 64 KB
    float*  Eta   = (float*)p;   p += (size_t)B_ * N_ * H_ * 4;           // 1 MB
    float4* kv    = (float4*)p;  p += (size_t)B_ * N_ * H_ * 16;          // 4 MB
    float2* accum = (float2*)p;  p += (size_t)KC * B_ * N_ * H_ * 8;      // 32 MB

    pack_all<<<IND_ + 2 * H_, 128, 0, stream>>>(Wx_w, Wa_w, Ua_w, WxT4, WaT4, UaT4);

    prep4<<<(B_ * N_) / RR, 128, 0, stream>>>(word_vecs, WxT4, Wx_b,
                                              WaT4, Wa_b, UaT4, Ua_b,
                                              mask, Eta, kv);

    dim3 grid(KC, N_ / QQ, B_);
    attn4<<<grid, 128, 0, stream>>>(Eta, kv, accum);

    fin4<<<(B_ * N_ * H_) / 256, 256, 0, stream>>>(accum, out);
}